// Round 17
// baseline (98.075 us; speedup 1.0000x reference)
//
#include <hip/hip_runtime.h>
#include <hip/hip_bf16.h>

// attention_11269994185437: B=4, C=256, CQK=32, H=W=64 -> N=4096
// out = gamma * (V @ P) + x,  P[n,m] = softmax over m of S[n,m], S = Q^T K.
// Qt pre-scaled by L2E: S' = L2E*S. cbias[b][n] = -log2(sum_m exp2(S'[n,m])).
// k_rowstats: S^T = K*Q^T, 8 waves, n-tile 64, K-frag reuse x2.
// k_attn_out: BALANCED waves -- every wave both produces one E sub-tile
//   (u=w&1, mf=w>>1; 16 exp2/interval) and consumes PV(j-1) for c-slice w*32
//   (acc[4], 16 fp8 MFMA). Order: S(j) MFMA -> PV(j-1) -> E(j) chain.
//   One __syncthreads per interval; V direct-to-register; bf16 partials.
// k_comb: sum bf16 partials, LDS-transpose [m][c]->[c][m], out = g*sum + x.

#define NB 4
#define CC 256
#define NN 4096
#define L2E 1.44269504088896340f

typedef short  short4v  __attribute__((ext_vector_type(4)));
typedef short  short8v  __attribute__((ext_vector_type(8)));
typedef __bf16 bf16x8   __attribute__((ext_vector_type(8)));
typedef float  f32x4    __attribute__((ext_vector_type(4)));
typedef float  f32x16   __attribute__((ext_vector_type(16)));
typedef unsigned long u64x2 __attribute__((ext_vector_type(2)));
typedef unsigned int u32;

#define AS1 __attribute__((address_space(1)))
#define AS3 __attribute__((address_space(3)))

static __device__ __forceinline__ void gload16(const void* g, void* l) {
  __builtin_amdgcn_global_load_lds((const AS1 u32*)g, (AS3 u32*)l, 16, 0, 0);
}

static __device__ __forceinline__ unsigned short f2bf(float f) {
  union { __bf16 h; unsigned short u; } v; v.h = (__bf16)f; return v.u;
}
static __device__ __forceinline__ float bf2f(unsigned short u) {
  union { unsigned u; float f; } v; v.u = (u32)u << 16; return v.f;
}

union FragU { short8v s; bf16x8 b; unsigned u[4]; };

static __device__ __forceinline__ bf16x8 ld_frag(const unsigned short* p) {
  FragU u; u.s = *(const short8v*)p; return u.b;
}

static __device__ __forceinline__ f32x16 zero16() {
  f32x16 v;
#pragma unroll
  for (int i = 0; i < 16; ++i) v[i] = 0.0f;
  return v;
}

static __device__ __forceinline__ f32x16 mfma32(bf16x8 a, bf16x8 b, f32x16 c) {
  return __builtin_amdgcn_mfma_f32_32x32x16_bf16(a, b, c, 0, 0, 0);
}

// ---------------- Kernel 0: W -> bf16 row-major [320][256] ----------------
__global__ __launch_bounds__(256) void k_wcvt(
    const float* __restrict__ Wq, const float* __restrict__ Wk,
    const float* __restrict__ Wv, unsigned short* __restrict__ Wb)
{
  const int i4 = blockIdx.x * 256 + threadIdx.x;     // 80 blocks
  const int e = i4 * 4;
  const int row = e >> 8, c = e & 255;
  const float* src = (row < 32) ? (Wq + row * 256 + c)
                   : (row < 64) ? (Wk + (row - 32) * 256 + c)
                                : (Wv + (row - 64) * 256 + c);
  f32x4 v = *(const f32x4*)src;
  short4v s;
#pragma unroll
  for (int j = 0; j < 4; ++j) s[j] = (short)f2bf(v[j]);
  *(short4v*)(Wb + e) = s;
}

// ---------------- Kernel 1: QKV projection --------------------------------
// Qt[b][n][32] bf16 (L2E-scaled), Kt[b][n][32] bf16,
// V8[b][n>>5][(n>>3)&1][c][((n>>4)&1)*8 + (n&7)] fp8 e4m3.
__global__ __launch_bounds__(256) void k_proj(
    const float* __restrict__ x, const unsigned short* __restrict__ Wb,
    const float* __restrict__ bq, const float* __restrict__ bk,
    const float* __restrict__ bv,
    unsigned short* __restrict__ Qt, unsigned short* __restrict__ Kt,
    unsigned char* __restrict__ V8)
{
  __shared__ unsigned short xs[32][268];   // xs[n_local][c]
  const int t = threadIdx.x;
  const int b = blockIdx.y;
  const int n0 = blockIdx.x * 32;
  const int w = t >> 6, l = t & 63, h = l >> 5, col = l & 31;

  const float* xb = x + (size_t)b * CC * NN;
  {
    const int c_off = t >> 3, nl = 4 * (t & 7);
#pragma unroll
    for (int c0 = 0; c0 < CC; c0 += 32) {
      int c = c0 + c_off;
      f32x4 v4 = *(const f32x4*)(xb + (size_t)c * NN + n0 + nl);
#pragma unroll
      for (int j = 0; j < 4; ++j) xs[nl + j][c] = f2bf(v4[j]);
    }
  }
  __syncthreads();

  for (int f = w; f < 10; f += 4) {
    const float* bsrc; int rowbase; int mode; int wrow;
    if (f == 0)      { bsrc = bq; rowbase = 0;            mode = 0; wrow = 0; }
    else if (f == 1) { bsrc = bk; rowbase = 0;            mode = 1; wrow = 32; }
    else             { bsrc = bv; rowbase = (f - 2) * 32; mode = 2; wrow = 64 + rowbase; }

    f32x16 acc0 = zero16();
    const unsigned short* wr = Wb + (size_t)(wrow + col) * 256 + 8 * h;

#pragma unroll
    for (int k0 = 0; k0 < CC; k0 += 16) {
      FragU a;
      a.s = *(const short8v*)(wr + k0);
      const unsigned short* p0 = &xs[col][k0 + 8 * h];
      FragU b0;
      short4v t0a = *(const short4v*)p0, t0b = *(const short4v*)(p0 + 4);
#pragma unroll
      for (int j = 0; j < 4; ++j) { b0.s[j] = t0a[j]; b0.s[4 + j] = t0b[j]; }
      acc0 = mfma32(a.b, b0.b, acc0);
    }

    const int n = n0 + col;
#pragma unroll
    for (int q = 0; q < 4; ++q) {
      f32x4 bias4 = *(const f32x4*)(bsrc + rowbase + 8 * q + 4 * h);
      float vals[4];
#pragma unroll
      for (int i = 0; i < 4; ++i) vals[i] = acc0[4 * q + i] + bias4[i];
      if (mode == 2) {
        // V8 byte = (((b*128 + n>>5)*2 + kh)*256 + c)*16 + t16*8 + (n&7)
        const size_t tb = ((((size_t)b * 128 + (n >> 5)) * 2 + ((n >> 3) & 1)) * 256) * 16
                          + ((n >> 4) & 1) * 8 + (n & 7);
        u32 w01 = __builtin_amdgcn_cvt_pk_fp8_f32(vals[0], vals[1], 0, false);
        u32 w23 = __builtin_amdgcn_cvt_pk_fp8_f32(vals[2], vals[3], 0, false);
        const int cb0 = rowbase + 8 * q + 4 * h;
        V8[tb + (size_t)(cb0 + 0) * 16] = (unsigned char)(w01 & 0xff);
        V8[tb + (size_t)(cb0 + 1) * 16] = (unsigned char)((w01 >> 8) & 0xff);
        V8[tb + (size_t)(cb0 + 2) * 16] = (unsigned char)(w23 & 0xff);
        V8[tb + (size_t)(cb0 + 3) * 16] = (unsigned char)((w23 >> 8) & 0xff);
      } else {
        unsigned short* dst = (mode == 0) ? Qt : Kt;
        const float scale = (mode == 0) ? L2E : 1.0f;   // fold L2E into Q
        short4v s4;
#pragma unroll
        for (int i = 0; i < 4; ++i) s4[i] = (short)f2bf(vals[i] * scale);
        *(short4v*)(dst + ((size_t)b * NN + n) * 32 + 8 * q + 4 * h) = s4;
      }
    }
  }
}

// ---------------- Kernel 2: row sums -> cbias (transposed MFMA) -----------
__global__ __launch_bounds__(512) void k_rowstats(
    const unsigned short* __restrict__ Qt, const unsigned short* __restrict__ Kt,
    float* __restrict__ cbias)
{
  __shared__ float ssum[8][64];
  const int t = threadIdx.x;
  const int w = t >> 6, l = t & 63, h = l >> 5, col = l & 31;
  const int b = blockIdx.y;
  const int n0 = blockIdx.x * 64;
  const unsigned short* Qb = Qt + (size_t)b * NN * 32;
  const unsigned short* Kb = Kt + (size_t)b * NN * 32;

  bf16x8 bq00 = ld_frag(Qb + (size_t)(n0 + col) * 32 + 8 * h);
  bf16x8 bq01 = ld_frag(Qb + (size_t)(n0 + col) * 32 + 16 + 8 * h);
  bf16x8 bq10 = ld_frag(Qb + (size_t)(n0 + 32 + col) * 32 + 8 * h);
  bf16x8 bq11 = ld_frag(Qb + (size_t)(n0 + 32 + col) * 32 + 16 + 8 * h);

  float acc0 = 0.0f, acc1 = 0.0f;
  const int mbase = w * (NN / 8);
#pragma unroll 2
  for (int mt = 0; mt < 16; ++mt) {
    const int m0 = mbase + mt * 32;
    bf16x8 ak0 = ld_frag(Kb + (size_t)(m0 + col) * 32 + 8 * h);
    bf16x8 ak1 = ld_frag(Kb + (size_t)(m0 + col) * 32 + 16 + 8 * h);
    f32x16 S0 = zero16(), S1 = zero16();
    S0 = mfma32(ak0, bq00, S0);
    S0 = mfma32(ak1, bq01, S0);
    S1 = mfma32(ak0, bq10, S1);
    S1 = mfma32(ak1, bq11, S1);
    float p0 = 0.0f, p1 = 0.0f, p2 = 0.0f, p3 = 0.0f;
#pragma unroll
    for (int r = 0; r < 8; ++r) {
      p0 += __builtin_amdgcn_exp2f(S0[r]);
      p1 += __builtin_amdgcn_exp2f(S0[8 + r]);
      p2 += __builtin_amdgcn_exp2f(S1[r]);
      p3 += __builtin_amdgcn_exp2f(S1[8 + r]);
    }
    acc0 += p0 + p1;
    acc1 += p2 + p3;
  }
  acc0 += __shfl_xor(acc0, 32);
  acc1 += __shfl_xor(acc1, 32);

  if (l < 32) { ssum[w][l] = acc0; ssum[w][32 + l] = acc1; }
  __syncthreads();

  if (t < 64) {
    float s = 0.0f;
#pragma unroll
    for (int wv = 0; wv < 8; ++wv) s += ssum[wv][t];
    cbias[(size_t)b * NN + n0 + t] = -__builtin_amdgcn_logf(s);
  }
}

// ---------------- Kernel 3: out^T = E^T * V^T, balanced waves -------------
// grid 128*nsplit (XCD-swizzled), 8 waves (512 thr). m-tile 128, all 256 c.
// Wave w: E sub-tile (u=w&1, mf=w>>1); PV c-slice w*32 (acc[4]).
// Interval j: S(j) MFMAs -> PV(j-1) 16 MFMAs -> E(j) chain -> barrier.
#define V_ISSUE(SET, TJ)                                                       \
  {                                                                            \
    const char* vg_ = vg + (size_t)(TJ) * 8192;                                \
    SET##A = *(const u64x2*)(vg_);                                             \
    SET##B = *(const u64x2*)(vg_ + 8192);                                      \
  }

#define PV_INT(EBSEL, vA, vB)                                                  \
  {                                                                            \
    const char* eb0_ = &ebuf[EBSEL][0][l * 16];                                \
    const char* eb1_ = &ebuf[EBSEL][1][l * 16];                                \
    u64x2 e00 = *(const u64x2*)(eb0_);                                         \
    u64x2 e01 = *(const u64x2*)(eb0_ + 1024);                                  \
    u64x2 e02 = *(const u64x2*)(eb0_ + 2048);                                  \
    u64x2 e03 = *(const u64x2*)(eb0_ + 3072);                                  \
    u64x2 e10 = *(const u64x2*)(eb1_);                                         \
    u64x2 e11 = *(const u64x2*)(eb1_ + 1024);                                  \
    u64x2 e12 = *(const u64x2*)(eb1_ + 2048);                                  \
    u64x2 e13 = *(const u64x2*)(eb1_ + 3072);                                  \
    long va0 = (long)vA[0], va1 = (long)vA[1];                                 \
    long vb0 = (long)vB[0], vb1 = (long)vB[1];                                 \
    acc[0] = __builtin_amdgcn_mfma_f32_32x32x16_fp8_fp8((long)e00[0], va0, acc[0], 0, 0, 0); \
    acc[1] = __builtin_amdgcn_mfma_f32_32x32x16_fp8_fp8((long)e01[0], va0, acc[1], 0, 0, 0); \
    acc[2] = __builtin_amdgcn_mfma_f32_32x32x16_fp8_fp8((long)e02[0], va0, acc[2], 0, 0, 0); \
    acc[3] = __builtin_amdgcn_mfma_f32_32x32x16_fp8_fp8((long)e03[0], va0, acc[3], 0, 0, 0); \
    acc[0] = __builtin_amdgcn_mfma_f32_32x32x16_fp8_fp8((long)e00[1], va1, acc[0], 0, 0, 0); \
    acc[1] = __builtin_amdgcn_mfma_f32_32x32x16_fp8_fp8((long)e01[1], va1, acc[1], 0, 0, 0); \
    acc[2] = __builtin_amdgcn_mfma_f32_32x32x16_fp8_fp8((long)e02[1], va1, acc[2], 0, 0, 0); \
    acc[3] = __builtin_amdgcn_mfma_f32_32x32x16_fp8_fp8((long)e03[1], va1, acc[3], 0, 0, 0); \
    acc[0] = __builtin_amdgcn_mfma_f32_32x32x16_fp8_fp8((long)e10[0], vb0, acc[0], 0, 0, 0); \
    acc[1] = __builtin_amdgcn_mfma_f32_32x32x16_fp8_fp8((long)e11[0], vb0, acc[1], 0, 0, 0); \
    acc[2] = __builtin_amdgcn_mfma_f32_32x32x16_fp8_fp8((long)e12[0], vb0, acc[2], 0, 0, 0); \
    acc[3] = __builtin_amdgcn_mfma_f32_32x32x16_fp8_fp8((long)e13[0], vb0, acc[3], 0, 0, 0); \
    acc[0] = __builtin_amdgcn_mfma_f32_32x32x16_fp8_fp8((long)e10[1], vb1, acc[0], 0, 0, 0); \
    acc[1] = __builtin_amdgcn_mfma_f32_32x32x16_fp8_fp8((long)e11[1], vb1, acc[1], 0, 0, 0); \
    acc[2] = __builtin_amdgcn_mfma_f32_32x32x16_fp8_fp8((long)e12[1], vb1, acc[2], 0, 0, 0); \
    acc[3] = __builtin_amdgcn_mfma_f32_32x32x16_fp8_fp8((long)e13[1], vb1, acc[3], 0, 0, 0); \
  }

#define K3_ITER(J, CUR, NXT)                                                   \
  if ((J) <= KJ) {                                                             \
    const int j_ = (J);                                                        \
    /* stage Q(j+1) */                                                         \
    if (j_ + 1 < KJ && ll == l) {                                              \
      const size_t qoff_ = (size_t)(2 * j_ + 2) * 2048;                        \
      const int qs_ = (j_ + 1) & 1;                                            \
      gload16(qsrc + qoff_, &qbuf[qs_][0][w * 256]);                           \
      gload16(qsrc + qoff_ + 2048, &qbuf[qs_][1][w * 256]);                    \
    }                                                                          \
    /* issue V tiles (2j, 2j+1) for PV(j) next interval */                     \
    if (j_ < KJ) V_ISSUE(NXT, 2 * j_)                                          \
    /* S(j) for this wave's (up, mfp) */                                       \
    f32x16 S;                                                                  \
    if (j_ < KJ) {                                                             \
      const char* qb = &qbuf[j_ & 1][up][0];                                   \
      FragU fq0, fq1;                                                          \
      fq0.s = *(const short8v*)(qb + l * 16);                                  \
      fq1.s = *(const short8v*)(qb + 1024 + l * 16);                           \
      S = zero16();                                                            \
      S = mfma32(fq0.b, bk0, S);                                               \
      S = mfma32(fq1.b, bk1, S);                                               \
    }                                                                          \
    /* PV(j-1): 16 fp8 MFMAs (covers S latency) */                             \
    if (j_ > 0) {                                                              \
      __builtin_amdgcn_s_setprio(1);                                          \
      PV_INT((j_ - 1) & 1, CUR##A, CUR##B)                                     \
      __builtin_amdgcn_s_setprio(0);                                          \
    }                                                                          \
    /* E(j) chain -> ebuf */                                                   \
    if (j_ < KJ) {                                                             \
      float e[16];                                                             \
      const float* cbi = cb + (2 * j_ + up) * 32;                              \
      _Pragma("unroll")                                                        \
      for (int q = 0; q < 4; ++q) {                                            \
        f32x4 cb4 = *(const f32x4*)(cbi + 8 * q + 4 * h);                      \
        _Pragma("unroll")                                                      \
        for (int i = 0; i < 4; ++i)                                            \
          e[4 * q + i] = __builtin_amdgcn_exp2f(S[4 * q + i] + cb4[i]);        \
      }                                                                        \
      u32 wA = __builtin_amdgcn_cvt_pk_fp8_f32(e[0], e[1], 0, false);          \
      wA = __builtin_amdgcn_cvt_pk_fp8_f32(e[2], e[3], wA, true);              \
      u32 wB = __builtin_amdgcn_cvt_pk_fp8_f32(e[4], e[5], 0, false);          \
      wB = __builtin_amdgcn_cvt_pk_fp8_f32(e[6], e[7], wB, true);              \
      u32 wC = __builtin_amdgcn_cvt_pk_fp8_f32(e[8], e[9], 0, false);          \
      wC = __builtin_amdgcn_cvt_pk_fp8_f32(e[10], e[11], wC, true);            \
      u32 wD = __builtin_amdgcn_cvt_pk_fp8_f32(e[12], e[13], 0, false);        \
      wD = __builtin_amdgcn_cvt_pk_fp8_f32(e[14], e[15], wD, true);            \
      asm("v_permlane32_swap_b32 %0, %1" : "+v"(wA), "+v"(wB));                \
      asm("v_permlane32_swap_b32 %0, %1" : "+v"(wC), "+v"(wD));                \
      u64x2 ev;                                                                \
      ev[0] = ((unsigned long)wB << 32) | wA;                                  \
      ev[1] = ((unsigned long)wD << 32) | wC;                                  \
      *(u64x2*)(&ebuf[j_ & 1][up][mfp * 1024 + l * 16]) = ev;                  \
    }                                                                          \
    if (j_ < KJ) __syncthreads();                                              \
  }

__global__ __launch_bounds__(512) void k_attn_out(
    const unsigned short* __restrict__ Qt, const unsigned short* __restrict__ Kt,
    const unsigned char* __restrict__ V8,
    const float* __restrict__ cbias,
    unsigned short* __restrict__ pout,
    int nsplit, int nlen)
{
  __shared__ __align__(16) char qbuf[2][2][2048];  // [buf][u] Q frag-linear
  __shared__ __align__(16) char ebuf[2][2][4096];  // [buf][u] E A-frags [mf][lane][16B]

  const int wg = (int)blockIdx.x;
  const int chunk = (int)gridDim.x >> 3;           // blocks per XCD (bijective)
  const int id2 = (wg & 7) * chunk + (wg >> 3);
  const int per_b = 32 * nsplit;                   // m-tiles(128) per batch * nsplit
  const int b = id2 / per_b;
  const int rem = id2 - b * per_b;
  const int ns = rem >> 5;
  const int m0 = (rem & 31) * 128;
  const int nbeg = ns * nlen;

  const int t = threadIdx.x;
  const int w = t >> 6, l = t & 63, h = l >> 5, col = l & 31;
  const int up = w & 1;                            // E tile within interval
  const int mfp = w >> 1;                          // E m-frag
  const int ccons = w * 32;                        // PV c-slice

  const unsigned short* Kb = Kt + (size_t)b * NN * 32;
  const float* cb = cbias + (size_t)b * NN + nbeg;

  // K fragments for this wave's m-frag (B operand of S), loop-invariant
  bf16x8 bk0 = ld_frag(Kb + (size_t)(m0 + 32 * mfp + col) * 32 + 8 * h);
  bf16x8 bk1 = ld_frag(Kb + (size_t)(m0 + 32 * mfp + col) * 32 + 16 + 8 * h);

  // Q staging: per tile 128 chunks of 16B; all 8 waves, lanes 0-15.
  const int ll = l & 15;
  const size_t gqoff = (size_t)(((w & 1) * 16 + ll) * 64 + ((w >> 1) & 1) * 16
                                + (w >> 2) * 32);
  const char* qsrc = (const char*)Qt + ((size_t)b * NN + nbeg) * 64 + gqoff;

  // V base: V8[b][nt][kh=h][c=ccons+col][16B]; per tile += 8192
  const char* vg = (const char*)V8
      + (((size_t)b * 128 + (nbeg >> 5)) * 2 + h) * 4096
      + (size_t)(ccons + col) * 16;

  f32x16 acc[4];
#pragma unroll
  for (int mf = 0; mf < 4; ++mf) acc[mf] = zero16();

  u64x2 S0A, S0B, S1A, S1B;       // V reg double buffer (tile pair each)
  S0A = S0B = S1A = S1B = (u64x2)0;

  const int KJ = nlen >> 6;                        // intervals of 64 n

  // ---- prologue: stage Q interval 0 ----
  if (ll == l) {
    gload16(qsrc, &qbuf[0][0][w * 256]);
    gload16(qsrc + 2048, &qbuf[0][1][w * 256]);
  }
  __syncthreads();

  for (int jj = 0; jj <= KJ; jj += 2) {
    K3_ITER(jj,     S0, S1)      // even: PV uses S0, issues S1
    K3_ITER(jj + 1, S1, S0)      // odd : PV uses S1, issues S0
  }

  // ---- epilogue: write bf16 D slice (128m x 32c) [m][c]-major ----
  {
    unsigned short* pb = pout + (((size_t)ns * NB + b) * NN + m0) * CC + ccons;
#pragma unroll
    for (int mf = 0; mf < 4; ++mf)
#pragma unroll
      for (int r = 0; r < 16; ++r) {
        int mloc = 32 * mf + (r & 3) + 8 * (r >> 2) + 4 * h;
        pb[(size_t)mloc * CC + col] = f2bf(acc[mf][r]);
      }
  }
}

// ---------------- Kernel 4: combine + transpose + residual ----------------
__global__ __launch_bounds__(256) void k_comb(
    const unsigned short* __restrict__ pout, const float* __restrict__ x,
    const float* __restrict__ gamma, float* __restrict__ out, int nsplit)
{
  __shared__ float ld[64][65];
  const size_t STRIDE = (size_t)NB * CC * NN;
  const int t = threadIdx.x;
  const int m0 = blockIdx.x * 64, c0 = blockIdx.y * 64, b = blockIdx.z;
  const int ci = t & 63, mo = t >> 6;

  const unsigned short* pb = pout + ((size_t)b * NN + m0) * CC + c0;
#pragma unroll
  for (int rep = 0; rep < 16; ++rep) {
    const int mi = 4 * rep + mo;
    float s = bf2f(pb[(size_t)mi * CC + ci]);
    for (int ns = 1; ns < nsplit; ++ns)
      s += bf2f(pb[ns * STRIDE + (size_t)mi * CC + ci]);
    ld[mi][ci] = s;
  }
  __syncthreads();

  const float g = gamma[0];
  const int mi2 = t & 63;
#pragma unroll
  for (int rep = 0; rep < 16; ++rep) {
    const int cj = 4 * rep + mo;
    const size_t idx = ((size_t)b * CC + c0 + cj) * NN + m0 + mi2;
    out[idx] = g * ld[mi2][cj] + x[idx];
  }
}

// ---------------- launch ---------------------------------------------------
extern "C" void kernel_launch(void* const* d_in, const int* in_sizes, int n_in,
                              void* d_out, int out_size, void* d_ws, size_t ws_size,
                              hipStream_t stream) {
  const float* x     = (const float*)d_in[0];
  const float* Wq    = (const float*)d_in[1];
  const float* bq    = (const float*)d_in[2];
  const float* Wk    = (const float*)d_in[3];
  const float* bk    = (const float*)d_in[4];
  const float* Wv    = (const float*)d_in[5];
  const float* bv    = (const float*)d_in[6];
  const float* gamma = (const float*)d_in[7];
  float* out = (float*)d_out;

  char* ws = (char*)d_ws;
  unsigned short* Qt = (unsigned short*)(ws);                      // 1 MB
  unsigned short* Kt = (unsigned short*)(ws + (1u << 20));         // 1 MB
  unsigned char*  V8 = (unsigned char*)(ws + (2u << 20));          // 4 MB
  unsigned short* Wb = (unsigned short*)(ws + (6u << 20));         // 160 KB
  float* cbias = (float*)(ws + (10u << 20) + (2u << 18));          // 64 KB
  const size_t POUT_OFF = (11u << 20);
  unsigned short* pout = (unsigned short*)(ws + POUT_OFF);
  const size_t PART_BYTES = (size_t)NB * CC * NN * 2;              // 8.4 MB (bf16)

  int nsplit = (ws_size >= POUT_OFF + 2 * PART_BYTES) ? 2 : 1;

  k_wcvt<<<dim3(80), 256, 0, stream>>>(Wq, Wk, Wv, Wb);
  k_proj<<<dim3(NN / 32, NB), 256, 0, stream>>>(x, Wb, bq, bk, bv, Qt, Kt, V8);
  k_rowstats<<<dim3(NN / 64, NB), 512, 0, stream>>>(Qt, Kt, cbias);
  k_attn_out<<<dim3(128 * nsplit), 512, 0, stream>>>(
      Qt, Kt, V8, cbias, pout, nsplit, NN / nsplit);
  k_comb<<<dim3(NN / 64, CC / 64, NB), 256, 0, stream>>>(pout, x, gamma, out, nsplit);
}